// Round 1
// baseline (8998.090 us; speedup 1.0000x reference)
//
#include <hip/hip_runtime.h>
#include <math.h>

// Sizes fixed by the problem.
#define B_TOT 131072
#define M_N   1024
#define BS    128      // Cholesky block size
#define NBK   8        // M_N / BS

// Workspace layout (bytes). Total ~20.1 MB.
enum : size_t {
    OFF_K  = 0,                          // fp64 K / L           8 MB
    OFF_W  = (size_t)8 << 20,            // fp64 W = L^-1        8 MB
    OFF_PD = (size_t)16 << 20,           // fp64 params (6)
    OFF_PF = ((size_t)16 << 20) + 256,   // fp32 params (6)
    OFF_ZD = ((size_t)16 << 20) + 512,   // fp64 Zs [1024][5]    40960
    OFF_ZT = OFF_ZD + (size_t)M_N * 5 * 8,   // fp32 Zs_t [5][1024]  20480
    OFF_WT = OFF_ZT + (size_t)M_N * 5 * 4,   // fp32 Wt [l][j]       4 MB
};

__device__ __constant__ double c_zscale[5] = {0.15, 0.1, 0.05, 800.0, 20.0};
__device__ __constant__ double c_zshift[5] = {0.0, 0.0, 0.0, 600.0, 5.0};

// ---------------- params: inv_ls, prior_var (fp64 + fp32) ----------------
__global__ void k_prep(const float* __restrict__ log_ls, const float* __restrict__ log_var,
                       double* __restrict__ pd, float* __restrict__ pf) {
    int t = threadIdx.x;
    if (t < 5) {
        double ls  = exp((double)log_ls[t]);
        double inv = 1.0 / (ls + 1e-8);
        pd[t] = inv; pf[t] = (float)inv;
    }
    if (t == 5) {
        double pv = exp((double)log_var[0]);
        pd[5] = pv; pf[5] = (float)pv;
    }
}

// ---------------- scaled inducing points ----------------
__global__ void k_prep_z(const float* __restrict__ Zraw, const double* __restrict__ pd,
                         double* __restrict__ Zs_d, float* __restrict__ Zs_t) {
    int m = blockIdx.x * 256 + threadIdx.x;
    if (m >= M_N) return;
#pragma unroll
    for (int d = 0; d < 5; ++d) {
        double z  = (double)Zraw[m * 5 + d] * c_zscale[d] + c_zshift[d];
        double zs = z * pd[d];
        Zs_d[m * 5 + d]  = zs;
        Zs_t[d * M_N + m] = (float)zs;   // transposed for coalesced main-kernel loads
    }
}

// ---------------- K = matern52 + jitter (fp64) ----------------
__global__ void k_build_K(const double* __restrict__ Zs_d, const double* __restrict__ pd,
                          double* __restrict__ Kd) {
    int i = blockIdx.y * 16 + threadIdx.y;
    int j = blockIdx.x * 16 + threadIdx.x;
    double d2 = 0.0;
#pragma unroll
    for (int d = 0; d < 5; ++d) {
        double df = Zs_d[i * 5 + d] - Zs_d[j * 5 + d];
        d2 += df * df;
    }
    double dd = d2 + 1e-8;
    double dist = sqrt(dd);
    double s = 2.2360679774997896 * dist;
    double v = pd[5] * (1.0 + s + (5.0 / 3.0) * dd) * exp(-s);
    if (i == j) v += 1e-4;
    Kd[(size_t)i * M_N + j] = v;
}

// ---------------- Cholesky diag block factor + in-LDS inverse of L11 ----------------
__global__ __launch_bounds__(1024) void k_chol_diag(double* __restrict__ Kd,
                                                    double* __restrict__ Wd, int kb) {
    __shared__ double As[BS][132];   // pad 132: 2-way-max bank aliasing (free)
    __shared__ double invd[BS];
    int tid = threadIdx.x;
    int r0 = kb * BS;
    for (int idx = tid; idx < BS * BS; idx += 1024) {
        int r = idx >> 7, c = idx & 127;
        As[r][c] = Kd[(size_t)(r0 + r) * M_N + r0 + c];
    }
    __syncthreads();
    // left-looking factor; 8 threads per row
    int r = tid >> 3, s = tid & 7;
    for (int j = 0; j < BS; ++j) {
        double part = 0.0;
        if (r >= j) {
            for (int t = s; t < j; t += 8) part += As[r][t] * As[j][t];
            part += __shfl_xor(part, 1);
            part += __shfl_xor(part, 2);
            part += __shfl_xor(part, 4);
        }
        if (r == j && s == 0) {
            double cjj = As[j][j] - part;
            double dg = sqrt(cjj);
            As[j][j] = dg;
            invd[j] = 1.0 / dg;
        }
        __syncthreads();
        if (r > j && s == 0) As[r][j] = (As[r][j] - part) * invd[j];
        __syncthreads();
    }
    // W11 = inv(L11): forward substitution, one column per wave (16 waves)
    int wid = tid >> 6, lane = tid & 63;
    for (int c = wid; c < BS; c += 16) {
        double w0 = 0.0, w1 = 0.0;
        int t0 = lane, t1 = lane + 64;
        for (int rr = c; rr < BS; ++rr) {
            double p = 0.0;
            if (t0 >= c && t0 < rr) p += As[rr][t0] * w0;
            if (t1 >= c && t1 < rr) p += As[rr][t1] * w1;
#pragma unroll
            for (int off = 1; off < 64; off <<= 1) p += __shfl_xor(p, off);
            double wr = ((rr == c) ? 1.0 - p : -p) * invd[rr];
            if (t0 == rr) w0 = wr;
            if (t1 == rr) w1 = wr;
        }
        if (t0 >= c) Wd[(size_t)(r0 + t0) * M_N + r0 + c] = w0;
        if (t1 >= c) Wd[(size_t)(r0 + t1) * M_N + r0 + c] = w1;
    }
}

// ---------------- panel: L21 = A21 * W11^T (pure GEMM, no substitution) ----------------
__global__ __launch_bounds__(256) void k_chol_panel(double* __restrict__ Kd,
                                                    const double* __restrict__ Wd, int kb) {
    __shared__ double As[64][16];
    __shared__ double Ws[16][128];
    int tid = threadIdx.x;
    int row0 = (kb + 1) * BS + blockIdx.x * 64;
    int cb = kb * BS;
    int c = tid & 127, q = tid >> 7;   // thread: column c, 32-row strip q
    double acc[32];
#pragma unroll
    for (int i = 0; i < 32; ++i) acc[i] = 0.0;
    for (int tc = 0; tc < 8; ++tc) {
        int tb = tc * 16;
        for (int idx = tid; idx < 64 * 16; idx += 256) {
            int rr = idx >> 4, tt = idx & 15;
            As[rr][tt] = Kd[(size_t)(row0 + rr) * M_N + cb + tb + tt];
        }
        for (int idx = tid; idx < 128 * 16; idx += 256) {
            int cc = idx >> 4, tt = idx & 15;
            // W11 lower-triangular: upper part of the stored block is garbage -> 0
            Ws[tt][cc] = (tb + tt <= cc) ? Wd[(size_t)(cb + cc) * M_N + cb + tb + tt] : 0.0;
        }
        __syncthreads();
#pragma unroll
        for (int t = 0; t < 16; ++t) {
            double w = Ws[t][c];
#pragma unroll
            for (int i = 0; i < 32; ++i) acc[i] += As[q * 32 + i][t] * w;
        }
        __syncthreads();
    }
#pragma unroll
    for (int i = 0; i < 32; ++i)
        Kd[(size_t)(row0 + q * 32 + i) * M_N + cb + c] = acc[i];
}

// ---------------- trailing update: A22 -= L21 * L21^T (lower tiles only) ----------------
__global__ __launch_bounds__(256) void k_chol_update(double* __restrict__ Kd, int kb) {
    if (blockIdx.x > blockIdx.y) return;   // upper tiles untouched
    __shared__ double As2[64][17];
    __shared__ double Bs2[64][17];
    int tid = threadIdx.x;
    int base = (kb + 1) * BS;
    int gr0 = base + blockIdx.y * 64;
    int gc0 = base + blockIdx.x * 64;
    int cb = kb * BS;
    int tx = tid & 15, ty = tid >> 4;
    double acc[4][4];
#pragma unroll
    for (int i = 0; i < 4; ++i)
#pragma unroll
        for (int j = 0; j < 4; ++j) acc[i][j] = 0.0;
    for (int tc = 0; tc < 8; ++tc) {
        int tb = tc * 16;
        for (int idx = tid; idx < 1024; idx += 256) {
            int rr = idx >> 4, tt = idx & 15;
            As2[rr][tt] = Kd[(size_t)(gr0 + rr) * M_N + cb + tb + tt];
            Bs2[rr][tt] = Kd[(size_t)(gc0 + rr) * M_N + cb + tb + tt];
        }
        __syncthreads();
#pragma unroll
        for (int t = 0; t < 16; ++t) {
            double a[4], b[4];
#pragma unroll
            for (int i = 0; i < 4; ++i) a[i] = As2[ty * 4 + i][t];
#pragma unroll
            for (int j = 0; j < 4; ++j) b[j] = Bs2[tx * 4 + j][t];
#pragma unroll
            for (int i = 0; i < 4; ++i)
#pragma unroll
                for (int j = 0; j < 4; ++j) acc[i][j] += a[i] * b[j];
        }
        __syncthreads();
    }
#pragma unroll
    for (int i = 0; i < 4; ++i)
#pragma unroll
        for (int j = 0; j < 4; ++j)
            Kd[(size_t)(gr0 + ty * 4 + i) * M_N + gc0 + tx * 4 + j] -= acc[i][j];
}

// ---------------- trtri off-diag: W_ij = -W_ii * (sum_t L_it W_tj), by diagonal d ----------------
__global__ __launch_bounds__(256) void k_trtri(const double* __restrict__ Kd,
                                               double* __restrict__ Wd, int dd) {
    __shared__ double Ls[128][33];
    __shared__ double Ws2[32][65];
    __shared__ double Ps[128][65];
    int j = blockIdx.y;
    int i = j + dd;
    int ct = blockIdx.x;                 // 64-col tile
    int i0 = i * BS, j0 = j * BS, c0 = j0 + ct * 64;
    int tid = threadIdx.x;
    int rq = tid >> 3, cq = tid & 7;     // rows {rq,+32,+64,+96}, cols {8cq..8cq+7}
    double acc[4][8];
#pragma unroll
    for (int k = 0; k < 4; ++k)
#pragma unroll
        for (int c = 0; c < 8; ++c) acc[k][c] = 0.0;

    for (int tb = j; tb < i; ++tb) {
        for (int ch = 0; ch < 4; ++ch) {
            int tbase = tb * BS + ch * 32;
            for (int idx = tid; idx < 128 * 32; idx += 256) {
                int rr = idx >> 5, tt = idx & 31;
                Ls[rr][tt] = Kd[(size_t)(i0 + rr) * M_N + tbase + tt];
            }
            for (int idx = tid; idx < 32 * 64; idx += 256) {
                int tt = idx >> 6, cc = idx & 63;
                int gr = tbase + tt, gc = c0 + cc;
                Ws2[tt][cc] = (tb == j && gr < gc) ? 0.0 : Wd[(size_t)gr * M_N + gc];
            }
            __syncthreads();
#pragma unroll
            for (int tt = 0; tt < 32; ++tt) {
                double l_[4];
#pragma unroll
                for (int k = 0; k < 4; ++k) l_[k] = Ls[rq + 32 * k][tt];
#pragma unroll
                for (int k = 0; k < 4; ++k)
#pragma unroll
                    for (int c = 0; c < 8; ++c)
                        acc[k][c] += l_[k] * Ws2[tt][cq * 8 + c];
            }
            __syncthreads();
        }
    }
#pragma unroll
    for (int k = 0; k < 4; ++k)
#pragma unroll
        for (int c = 0; c < 8; ++c) Ps[rq + 32 * k][cq * 8 + c] = acc[k][c];
    __syncthreads();

    double a2[4][8];
#pragma unroll
    for (int k = 0; k < 4; ++k)
#pragma unroll
        for (int c = 0; c < 8; ++c) a2[k][c] = 0.0;
    for (int ch = 0; ch < 4; ++ch) {
        for (int idx = tid; idx < 128 * 32; idx += 256) {
            int rr = idx >> 5, tt = idx & 31;
            int col = ch * 32 + tt;      // W_ii lower-triangular: zero above diag
            Ls[rr][tt] = (col <= rr) ? Wd[(size_t)(i0 + rr) * M_N + i0 + col] : 0.0;
        }
        __syncthreads();
#pragma unroll
        for (int tt = 0; tt < 32; ++tt) {
            double l_[4];
#pragma unroll
            for (int k = 0; k < 4; ++k) l_[k] = Ls[rq + 32 * k][tt];
#pragma unroll
            for (int k = 0; k < 4; ++k)
#pragma unroll
                for (int c = 0; c < 8; ++c)
                    a2[k][c] += l_[k] * Ps[ch * 32 + tt][cq * 8 + c];
        }
        __syncthreads();
    }
#pragma unroll
    for (int k = 0; k < 4; ++k)
#pragma unroll
        for (int c = 0; c < 8; ++c)
            Wd[(size_t)(i0 + rq + 32 * k) * M_N + c0 + cq * 8 + c] = -a2[k][c];
}

// ---------------- cast W to fp32, transposed: Wt[l][j] = W[j][l] (0 above diag) ----------------
__global__ void k_cast(const double* __restrict__ Wd, float* __restrict__ Wt) {
    int idx = blockIdx.x * 256 + threadIdx.x;
    int l = idx >> 10, jj = idx & 1023;
    Wt[idx] = (jj >= l) ? (float)Wd[(size_t)jj * M_N + l] : 0.0f;
}

// ---------------- main fused kernel: k tile -> y = W k -> red -> sqrt ----------------
__global__ __launch_bounds__(256) void k_main(const float* __restrict__ x_star,
                                              const float* __restrict__ pf,
                                              const float* __restrict__ Zs_t,
                                              const float* __restrict__ Wt,
                                              float* __restrict__ out, int Bq) {
    __shared__ float kl[16 * 1025];   // padded stride 1025: bank = (r + l) % 32
    __shared__ float xs[16][5];
    int tid = threadIdx.x;
    int r0 = blockIdx.x * 16;
    if (tid < 80) {
        int rr = tid / 5, d = tid % 5;
        float xv = (r0 + rr < Bq) ? x_star[(size_t)(r0 + rr) * 5 + d] : 0.0f;
        xs[rr][d] = xv * pf[d];
    }
    float pv = pf[5];
    __syncthreads();
    // phase 1: k[16][1024] in LDS
    for (int it = 0; it < 4; ++it) {
        int m = it * 256 + tid;
        float z0 = Zs_t[m], z1 = Zs_t[1024 + m], z2 = Zs_t[2048 + m],
              z3 = Zs_t[3072 + m], z4 = Zs_t[4096 + m];
#pragma unroll
        for (int rr = 0; rr < 16; ++rr) {
            float dx0 = xs[rr][0] - z0, dx1 = xs[rr][1] - z1, dx2 = xs[rr][2] - z2,
                  dx3 = xs[rr][3] - z3, dx4 = xs[rr][4] - z4;
            float d2 = dx0 * dx0 + dx1 * dx1 + dx2 * dx2 + dx3 * dx3 + dx4 * dx4;
            float ddv = d2 + 1e-8f;
            float dist = sqrtf(ddv);
            float sv = 2.23606798f * dist;
            float kv = pv * (1.0f + sv + (5.0f / 3.0f) * ddv) * __expf(-sv);
            kl[rr * 1025 + m] = kv;
        }
    }
    __syncthreads();
    // phase 2: red = ||W k||^2, triangular at 512-col granularity
    int tr = tid >> 6, tc = tid & 63;
    const float* krow = kl + tr * 1025;
    float red[4] = {0.f, 0.f, 0.f, 0.f};
    for (int jc = 0; jc < 2; ++jc) {
        int j0 = jc * 512;
        int Lmax = jc ? 1024 : 512;
        float acc[4][8];
#pragma unroll
        for (int k = 0; k < 4; ++k)
#pragma unroll
            for (int c = 0; c < 8; ++c) acc[k][c] = 0.f;
#pragma unroll 4
        for (int l = 0; l < Lmax; ++l) {
            float kv[4];
            kv[0] = krow[l];
            kv[1] = krow[4 * 1025 + l];
            kv[2] = krow[8 * 1025 + l];
            kv[3] = krow[12 * 1025 + l];
            const float4* wp = (const float4*)(Wt + ((size_t)l << 10) + j0);
            float4 wa = wp[tc * 2];
            float4 wb = wp[tc * 2 + 1];
            float w[8] = {wa.x, wa.y, wa.z, wa.w, wb.x, wb.y, wb.z, wb.w};
#pragma unroll
            for (int k = 0; k < 4; ++k)
#pragma unroll
                for (int c = 0; c < 8; ++c)
                    acc[k][c] = fmaf(kv[k], w[c], acc[k][c]);
        }
#pragma unroll
        for (int k = 0; k < 4; ++k) {
            float s2 = 0.f;
#pragma unroll
            for (int c = 0; c < 8; ++c) s2 = fmaf(acc[k][c], acc[k][c], s2);
            red[k] += s2;
        }
    }
#pragma unroll
    for (int off = 1; off < 64; off <<= 1) {
#pragma unroll
        for (int k = 0; k < 4; ++k) red[k] += __shfl_xor(red[k], off);
    }
    if (tc == 0) {
#pragma unroll
        for (int k = 0; k < 4; ++k) {
            int row = r0 + tr + 4 * k;
            if (row < Bq) out[row] = sqrtf(fmaxf(pv - red[k], 1e-6f));
        }
    }
}

extern "C" void kernel_launch(void* const* d_in, const int* in_sizes, int n_in,
                              void* d_out, int out_size, void* d_ws, size_t ws_size,
                              hipStream_t stream) {
    const float* x_star  = (const float*)d_in[0];
    const float* log_ls  = (const float*)d_in[1];
    const float* log_var = (const float*)d_in[2];
    const float* Z_raw   = (const float*)d_in[3];
    float* out = (float*)d_out;
    int Bq = in_sizes[0] / 5;

    char* ws = (char*)d_ws;
    double* Kd  = (double*)(ws + OFF_K);
    double* Wd  = (double*)(ws + OFF_W);
    double* pd  = (double*)(ws + OFF_PD);
    float*  pf  = (float*)(ws + OFF_PF);
    double* Zsd = (double*)(ws + OFF_ZD);
    float*  Zst = (float*)(ws + OFF_ZT);
    float*  Wt  = (float*)(ws + OFF_WT);

    k_prep<<<1, 64, 0, stream>>>(log_ls, log_var, pd, pf);
    k_prep_z<<<M_N / 256, 256, 0, stream>>>(Z_raw, pd, Zsd, Zst);
    k_build_K<<<dim3(M_N / 16, M_N / 16), dim3(16, 16), 0, stream>>>(Zsd, pd, Kd);

    for (int kb = 0; kb < NBK; ++kb) {
        k_chol_diag<<<1, 1024, 0, stream>>>(Kd, Wd, kb);
        int R = M_N - (kb + 1) * BS;
        if (R > 0) {
            k_chol_panel<<<R / 64, 256, 0, stream>>>(Kd, Wd, kb);
            k_chol_update<<<dim3(R / 64, R / 64), 256, 0, stream>>>(Kd, kb);
        }
    }
    for (int dd = 1; dd < NBK; ++dd)
        k_trtri<<<dim3(2, NBK - dd), 256, 0, stream>>>(Kd, Wd, dd);

    k_cast<<<(M_N * M_N) / 256, 256, 0, stream>>>(Wd, Wt);
    k_main<<<(Bq + 15) / 16, 256, 0, stream>>>(x_star, pf, Zst, Wt, out, Bq);
}

// Round 2
// 5907.678 us; speedup vs baseline: 1.5231x; 1.5231x over previous
//
#include <hip/hip_runtime.h>
#include <math.h>

// Sizes fixed by the problem.
#define B_TOT 131072
#define M_N   1024
#define BS    128      // Cholesky block size
#define NBK   8        // M_N / BS

typedef float  f32x4  __attribute__((ext_vector_type(4)));
typedef short  bf16x8 __attribute__((ext_vector_type(8)));

// Workspace layout (bytes). Total ~21.2 MB.
enum : size_t {
    OFF_K  = 0,                          // fp64 K / L           8 MB
    OFF_W  = (size_t)8 << 20,            // fp64 W = L^-1        8 MB
    OFF_PD = (size_t)16 << 20,           // fp64 params (6)
    OFF_PF = ((size_t)16 << 20) + 256,   // fp32 params (6)
    OFF_ZD = ((size_t)16 << 20) + 512,   // fp64 Zs [1024][5]    40960
    OFF_ZT = OFF_ZD + (size_t)M_N * 5 * 8,   // fp32 Zs_t [5][1024]  20480
    OFF_WPH = OFF_ZT + (size_t)M_N * 5 * 4,  // bf16 W packed hi     2 MB
    OFF_WPL = OFF_WPH + (size_t)M_N * M_N * 2,  // bf16 W packed lo  2 MB
    OFF_RED = OFF_WPL + (size_t)M_N * M_N * 2,  // f32 redp[2][B]    1 MB
};

__device__ __constant__ double c_zscale[5] = {0.15, 0.1, 0.05, 800.0, 20.0};
__device__ __constant__ double c_zshift[5] = {0.0, 0.0, 0.0, 600.0, 5.0};

static __device__ __forceinline__ unsigned short f2bf(float f) {
    unsigned u = __float_as_uint(f);
    unsigned r = (u + 0x7fff + ((u >> 16) & 1)) >> 16;   // RNE
    return (unsigned short)r;
}
static __device__ __forceinline__ float bf2f(unsigned short s) {
    return __uint_as_float(((unsigned)s) << 16);
}

// ---------------- params: inv_ls, prior_var (fp64 + fp32) ----------------
__global__ void k_prep(const float* __restrict__ log_ls, const float* __restrict__ log_var,
                       double* __restrict__ pd, float* __restrict__ pf) {
    int t = threadIdx.x;
    if (t < 5) {
        double ls  = exp((double)log_ls[t]);
        double inv = 1.0 / (ls + 1e-8);
        pd[t] = inv; pf[t] = (float)inv;
    }
    if (t == 5) {
        double pv = exp((double)log_var[0]);
        pd[5] = pv; pf[5] = (float)pv;
    }
}

// ---------------- scaled inducing points ----------------
__global__ void k_prep_z(const float* __restrict__ Zraw, const double* __restrict__ pd,
                         double* __restrict__ Zs_d, float* __restrict__ Zs_t) {
    int m = blockIdx.x * 256 + threadIdx.x;
    if (m >= M_N) return;
#pragma unroll
    for (int d = 0; d < 5; ++d) {
        double z  = (double)Zraw[m * 5 + d] * c_zscale[d] + c_zshift[d];
        double zs = z * pd[d];
        Zs_d[m * 5 + d]  = zs;
        Zs_t[d * M_N + m] = (float)zs;
    }
}

// ---------------- K = matern52 + jitter (fp64) ----------------
__global__ void k_build_K(const double* __restrict__ Zs_d, const double* __restrict__ pd,
                          double* __restrict__ Kd) {
    int i = blockIdx.y * 16 + threadIdx.y;
    int j = blockIdx.x * 16 + threadIdx.x;
    double d2 = 0.0;
#pragma unroll
    for (int d = 0; d < 5; ++d) {
        double df = Zs_d[i * 5 + d] - Zs_d[j * 5 + d];
        d2 += df * df;
    }
    double dd = d2 + 1e-8;
    double dist = sqrt(dd);
    double s = 2.2360679774997896 * dist;
    double v = pd[5] * (1.0 + s + (5.0 / 3.0) * dd) * exp(-s);
    if (i == j) v += 1e-4;
    Kd[(size_t)i * M_N + j] = v;
}

// ---------------- Cholesky diag block factor + in-LDS inverse of L11 ----------------
__global__ __launch_bounds__(1024) void k_chol_diag(double* __restrict__ Kd,
                                                    double* __restrict__ Wd, int kb) {
    __shared__ double As[BS][132];
    __shared__ double invd[BS];
    int tid = threadIdx.x;
    int r0 = kb * BS;
    for (int idx = tid; idx < BS * BS; idx += 1024) {
        int r = idx >> 7, c = idx & 127;
        As[r][c] = Kd[(size_t)(r0 + r) * M_N + r0 + c];
    }
    __syncthreads();
    int r = tid >> 3, s = tid & 7;
    for (int j = 0; j < BS; ++j) {
        double part = 0.0;
        if (r >= j) {
            for (int t = s; t < j; t += 8) part += As[r][t] * As[j][t];
            part += __shfl_xor(part, 1);
            part += __shfl_xor(part, 2);
            part += __shfl_xor(part, 4);
        }
        if (r == j && s == 0) {
            double cjj = As[j][j] - part;
            double dg = sqrt(cjj);
            As[j][j] = dg;
            invd[j] = 1.0 / dg;
        }
        __syncthreads();
        if (r > j && s == 0) As[r][j] = (As[r][j] - part) * invd[j];
        __syncthreads();
    }
    int wid = tid >> 6, lane = tid & 63;
    for (int c = wid; c < BS; c += 16) {
        double w0 = 0.0, w1 = 0.0;
        int t0 = lane, t1 = lane + 64;
        for (int rr = c; rr < BS; ++rr) {
            double p = 0.0;
            if (t0 >= c && t0 < rr) p += As[rr][t0] * w0;
            if (t1 >= c && t1 < rr) p += As[rr][t1] * w1;
#pragma unroll
            for (int off = 1; off < 64; off <<= 1) p += __shfl_xor(p, off);
            double wr = ((rr == c) ? 1.0 - p : -p) * invd[rr];
            if (t0 == rr) w0 = wr;
            if (t1 == rr) w1 = wr;
        }
        if (t0 >= c) Wd[(size_t)(r0 + t0) * M_N + r0 + c] = w0;
        if (t1 >= c) Wd[(size_t)(r0 + t1) * M_N + r0 + c] = w1;
    }
}

// ---------------- panel: L21 = A21 * W11^T ----------------
__global__ __launch_bounds__(256) void k_chol_panel(double* __restrict__ Kd,
                                                    const double* __restrict__ Wd, int kb) {
    __shared__ double As[64][16];
    __shared__ double Ws[16][128];
    int tid = threadIdx.x;
    int row0 = (kb + 1) * BS + blockIdx.x * 64;
    int cb = kb * BS;
    int c = tid & 127, q = tid >> 7;
    double acc[32];
#pragma unroll
    for (int i = 0; i < 32; ++i) acc[i] = 0.0;
    for (int tc = 0; tc < 8; ++tc) {
        int tb = tc * 16;
        for (int idx = tid; idx < 64 * 16; idx += 256) {
            int rr = idx >> 4, tt = idx & 15;
            As[rr][tt] = Kd[(size_t)(row0 + rr) * M_N + cb + tb + tt];
        }
        for (int idx = tid; idx < 128 * 16; idx += 256) {
            int cc = idx >> 4, tt = idx & 15;
            Ws[tt][cc] = (tb + tt <= cc) ? Wd[(size_t)(cb + cc) * M_N + cb + tb + tt] : 0.0;
        }
        __syncthreads();
#pragma unroll
        for (int t = 0; t < 16; ++t) {
            double w = Ws[t][c];
#pragma unroll
            for (int i = 0; i < 32; ++i) acc[i] += As[q * 32 + i][t] * w;
        }
        __syncthreads();
    }
#pragma unroll
    for (int i = 0; i < 32; ++i)
        Kd[(size_t)(row0 + q * 32 + i) * M_N + cb + c] = acc[i];
}

// ---------------- trailing update: A22 -= L21 * L21^T ----------------
__global__ __launch_bounds__(256) void k_chol_update(double* __restrict__ Kd, int kb) {
    if (blockIdx.x > blockIdx.y) return;
    __shared__ double As2[64][17];
    __shared__ double Bs2[64][17];
    int tid = threadIdx.x;
    int base = (kb + 1) * BS;
    int gr0 = base + blockIdx.y * 64;
    int gc0 = base + blockIdx.x * 64;
    int cb = kb * BS;
    int tx = tid & 15, ty = tid >> 4;
    double acc[4][4];
#pragma unroll
    for (int i = 0; i < 4; ++i)
#pragma unroll
        for (int j = 0; j < 4; ++j) acc[i][j] = 0.0;
    for (int tc = 0; tc < 8; ++tc) {
        int tb = tc * 16;
        for (int idx = tid; idx < 1024; idx += 256) {
            int rr = idx >> 4, tt = idx & 15;
            As2[rr][tt] = Kd[(size_t)(gr0 + rr) * M_N + cb + tb + tt];
            Bs2[rr][tt] = Kd[(size_t)(gc0 + rr) * M_N + cb + tb + tt];
        }
        __syncthreads();
#pragma unroll
        for (int t = 0; t < 16; ++t) {
            double a[4], b[4];
#pragma unroll
            for (int i = 0; i < 4; ++i) a[i] = As2[ty * 4 + i][t];
#pragma unroll
            for (int j = 0; j < 4; ++j) b[j] = Bs2[tx * 4 + j][t];
#pragma unroll
            for (int i = 0; i < 4; ++i)
#pragma unroll
                for (int j = 0; j < 4; ++j) acc[i][j] += a[i] * b[j];
        }
        __syncthreads();
    }
#pragma unroll
    for (int i = 0; i < 4; ++i)
#pragma unroll
        for (int j = 0; j < 4; ++j)
            Kd[(size_t)(gr0 + ty * 4 + i) * M_N + gc0 + tx * 4 + j] -= acc[i][j];
}

// ---------------- trtri off-diag blocks ----------------
__global__ __launch_bounds__(256) void k_trtri(const double* __restrict__ Kd,
                                               double* __restrict__ Wd, int dd) {
    __shared__ double Ls[128][33];
    __shared__ double Ws2[32][65];
    __shared__ double Ps[128][65];
    int j = blockIdx.y;
    int i = j + dd;
    int ct = blockIdx.x;
    int i0 = i * BS, j0 = j * BS, c0 = j0 + ct * 64;
    int tid = threadIdx.x;
    int rq = tid >> 3, cq = tid & 7;
    double acc[4][8];
#pragma unroll
    for (int k = 0; k < 4; ++k)
#pragma unroll
        for (int c = 0; c < 8; ++c) acc[k][c] = 0.0;

    for (int tb = j; tb < i; ++tb) {
        for (int ch = 0; ch < 4; ++ch) {
            int tbase = tb * BS + ch * 32;
            for (int idx = tid; idx < 128 * 32; idx += 256) {
                int rr = idx >> 5, tt = idx & 31;
                Ls[rr][tt] = Kd[(size_t)(i0 + rr) * M_N + tbase + tt];
            }
            for (int idx = tid; idx < 32 * 64; idx += 256) {
                int tt = idx >> 6, cc = idx & 63;
                int gr = tbase + tt, gc = c0 + cc;
                Ws2[tt][cc] = (tb == j && gr < gc) ? 0.0 : Wd[(size_t)gr * M_N + gc];
            }
            __syncthreads();
#pragma unroll
            for (int tt = 0; tt < 32; ++tt) {
                double l_[4];
#pragma unroll
                for (int k = 0; k < 4; ++k) l_[k] = Ls[rq + 32 * k][tt];
#pragma unroll
                for (int k = 0; k < 4; ++k)
#pragma unroll
                    for (int c = 0; c < 8; ++c)
                        acc[k][c] += l_[k] * Ws2[tt][cq * 8 + c];
            }
            __syncthreads();
        }
    }
#pragma unroll
    for (int k = 0; k < 4; ++k)
#pragma unroll
        for (int c = 0; c < 8; ++c) Ps[rq + 32 * k][cq * 8 + c] = acc[k][c];
    __syncthreads();

    double a2[4][8];
#pragma unroll
    for (int k = 0; k < 4; ++k)
#pragma unroll
        for (int c = 0; c < 8; ++c) a2[k][c] = 0.0;
    for (int ch = 0; ch < 4; ++ch) {
        for (int idx = tid; idx < 128 * 32; idx += 256) {
            int rr = idx >> 5, tt = idx & 31;
            int col = ch * 32 + tt;
            Ls[rr][tt] = (col <= rr) ? Wd[(size_t)(i0 + rr) * M_N + i0 + col] : 0.0;
        }
        __syncthreads();
#pragma unroll
        for (int tt = 0; tt < 32; ++tt) {
            double l_[4];
#pragma unroll
            for (int k = 0; k < 4; ++k) l_[k] = Ls[rq + 32 * k][tt];
#pragma unroll
            for (int k = 0; k < 4; ++k)
#pragma unroll
                for (int c = 0; c < 8; ++c)
                    a2[k][c] += l_[k] * Ps[ch * 32 + tt][cq * 8 + c];
        }
        __syncthreads();
    }
#pragma unroll
    for (int k = 0; k < 4; ++k)
#pragma unroll
        for (int c = 0; c < 8; ++c)
            Wd[(size_t)(i0 + rq + 32 * k) * M_N + c0 + cq * 8 + c] = -a2[k][c];
}

// ---------------- pack W into MFMA B-fragment order, bf16 hi/lo ----------------
// frag id fid = ((kc*4 + ki)*64 + jn); lane l element e:
//   B[k = kc*128 + ki*32 + (l>>4)*8 + e][j = jn*16 + (l&15)] = W[j][k] (0 if k > j)
__global__ void k_pack(const double* __restrict__ Wd, short* __restrict__ Wph,
                       short* __restrict__ Wpl) {
    int T = blockIdx.x * 256 + threadIdx.x;
    int lane = T & 63, fid = T >> 6;
    int jn = fid & 63, kik = fid >> 6;
    int ki = kik & 3, kc = kik >> 2;
    int j  = jn * 16 + (lane & 15);
    int kb = kc * 128 + ki * 32 + (lane >> 4) * 8;
    bf16x8 h, lo;
#pragma unroll
    for (int e = 0; e < 8; ++e) {
        int k = kb + e;
        float v = (k <= j) ? (float)Wd[(size_t)j * M_N + k] : 0.0f;
        unsigned short hb = f2bf(v);
        h[e]  = (short)hb;
        lo[e] = (short)f2bf(v - bf2f(hb));
    }
    size_t off = (size_t)fid * 512 + lane * 8;
    *(bf16x8*)(Wph + off) = h;
    *(bf16x8*)(Wpl + off) = lo;
}

// ---------------- main MFMA kernel: red_p = || W[:, panel] rows · k ||^2 partial ----------------
// grid (slabs, 2): 64 query rows per slab, 512 W-rows (output cols) per panel.
// k tile (64 x 128) computed on the fly into XOR-swizzled LDS as bf16 hi/lo.
__global__ __launch_bounds__(256, 2) void k_mm(const float* __restrict__ x_star,
                                               const float* __restrict__ pf,
                                               const float* __restrict__ Zs_t,
                                               const short* __restrict__ Wph,
                                               const short* __restrict__ Wpl,
                                               float* __restrict__ redp, int Bq) {
    __shared__ char kls[2][64 * 256];   // [hi/lo][row][256B], byte ^= (row&15)<<4
    __shared__ float red_l[64];
    int tid  = threadIdx.x;
    int slab = blockIdx.x, pp = blockIdx.y;
    int srow = tid & 63, g = tid >> 6;          // staging: row, l-group
    int w = g, lane = tid & 63;                 // compute: wave, lane
    int lrow = lane & 15, kgrp = lane >> 4;

    int qrow = slab * 64 + srow;
    int qc = (qrow < Bq) ? qrow : (Bq - 1);
    float xv0 = x_star[(size_t)qc * 5 + 0] * pf[0];
    float xv1 = x_star[(size_t)qc * 5 + 1] * pf[1];
    float xv2 = x_star[(size_t)qc * 5 + 2] * pf[2];
    float xv3 = x_star[(size_t)qc * 5 + 3] * pf[3];
    float xv4 = x_star[(size_t)qc * 5 + 4] * pf[4];
    float pv = pf[5];
    if (tid < 64) red_l[tid] = 0.0f;

    f32x4 acc[4][8];
#pragma unroll
    for (int mi = 0; mi < 4; ++mi)
#pragma unroll
        for (int nj = 0; nj < 8; ++nj) acc[mi][nj] = (f32x4)(0.0f);

    int jmax_w = (pp * 32 + w + 28) * 16 + 15;  // wave's max output column
    int KC = 4 * (pp + 1);

    for (int kc = 0; kc < KC; ++kc) {
        __syncthreads();                         // prior-chunk reads done
        // ---- stage k chunk: rows 0..63 x l in [kc*128, kc*128+128), hi/lo bf16 ----
        int lbase = kc * 128 + g * 32;
#pragma unroll 2
        for (int u = 0; u < 8; ++u) {
            unsigned long long hibits = 0, lobits = 0;
#pragma unroll
            for (int v = 0; v < 4; ++v) {
                int l = lbase + u * 4 + v;
                float dx0 = xv0 - Zs_t[l];
                float dx1 = xv1 - Zs_t[M_N + l];
                float dx2 = xv2 - Zs_t[2 * M_N + l];
                float dx3 = xv3 - Zs_t[3 * M_N + l];
                float dx4 = xv4 - Zs_t[4 * M_N + l];
                float d2 = dx0 * dx0 + dx1 * dx1 + dx2 * dx2 + dx3 * dx3 + dx4 * dx4;
                float ddv = d2 + 1e-8f;
                float dist = sqrtf(ddv);
                float sv = 2.23606798f * dist;
                float kvf = pv * (1.0f + sv + 1.66666667f * ddv) * __expf(-sv);
                unsigned short hb = f2bf(kvf);
                unsigned short lb = f2bf(kvf - bf2f(hb));
                hibits |= (unsigned long long)hb << (16 * v);
                lobits |= (unsigned long long)lb << (16 * v);
            }
            int cb  = g * 64 + u * 8;
            int off = srow * 256 + (cb ^ ((srow & 15) << 4));
            *(unsigned long long*)(&kls[0][off]) = hibits;
            *(unsigned long long*)(&kls[1][off]) = lobits;
        }
        __syncthreads();
        // ---- MFMA over this K chunk ----
        for (int ki = 0; ki < 4; ++ki) {
            int kmin = kc * 128 + ki * 32;
            if (kmin > jmax_w) break;            // wave-uniform, monotone in ki
            bf16x8 Ah[4], Al[4];
#pragma unroll
            for (int mi = 0; mi < 4; ++mi) {
                int row = mi * 16 + lrow;
                int cb  = ki * 64 + kgrp * 16;
                int off = row * 256 + (cb ^ ((row & 15) << 4));
                Ah[mi] = *(const bf16x8*)(&kls[0][off]);
                Al[mi] = *(const bf16x8*)(&kls[1][off]);
            }
#pragma unroll
            for (int nj = 0; nj < 8; ++nj) {
                int jng = pp * 32 + w + 4 * nj;
                if (kmin > jng * 16 + 15) continue;   // all-zero fragment of W
                size_t fo = ((size_t)((kc * 4 + ki) * 64 + jng)) * 512 + lane * 8;
                bf16x8 Bh = *(const bf16x8*)(Wph + fo);
                bf16x8 Bl = *(const bf16x8*)(Wpl + fo);
#pragma unroll
                for (int mi = 0; mi < 4; ++mi) {
                    acc[mi][nj] = __builtin_amdgcn_mfma_f32_16x16x32_bf16(Ah[mi], Bh, acc[mi][nj], 0, 0, 0);
                    acc[mi][nj] = __builtin_amdgcn_mfma_f32_16x16x32_bf16(Ah[mi], Bl, acc[mi][nj], 0, 0, 0);
                    acc[mi][nj] = __builtin_amdgcn_mfma_f32_16x16x32_bf16(Al[mi], Bh, acc[mi][nj], 0, 0, 0);
                }
            }
        }
    }

    // ---- epilogue: red[row] += sum over this wave's cols of y^2 ----
    // C layout: lane holds rows mi*16 + kgrp*4 + q, col jng*16 + lrow.
#pragma unroll
    for (int mi = 0; mi < 4; ++mi) {
#pragma unroll
        for (int q = 0; q < 4; ++q) {
            float s = 0.0f;
#pragma unroll
            for (int nj = 0; nj < 8; ++nj) s = fmaf(acc[mi][nj][q], acc[mi][nj][q], s);
            s += __shfl_xor(s, 1);
            s += __shfl_xor(s, 2);
            s += __shfl_xor(s, 4);
            s += __shfl_xor(s, 8);
            if (lrow == 0) atomicAdd(&red_l[mi * 16 + kgrp * 4 + q], s);
        }
    }
    __syncthreads();
    if (tid < 64) {
        int b = slab * 64 + tid;
        if (b < Bq) redp[(size_t)pp * Bq + b] = red_l[tid];
    }
}

// ---------------- final: out = sqrt(max(pv - red0 - red1, 1e-6)) ----------------
__global__ void k_fin(const float* __restrict__ redp, const float* __restrict__ pf,
                      float* __restrict__ out, int Bq) {
    int b = blockIdx.x * 256 + threadIdx.x;
    if (b < Bq) {
        float red = redp[b] + redp[(size_t)Bq + b];
        out[b] = sqrtf(fmaxf(pf[5] - red, 1e-6f));
    }
}

extern "C" void kernel_launch(void* const* d_in, const int* in_sizes, int n_in,
                              void* d_out, int out_size, void* d_ws, size_t ws_size,
                              hipStream_t stream) {
    const float* x_star  = (const float*)d_in[0];
    const float* log_ls  = (const float*)d_in[1];
    const float* log_var = (const float*)d_in[2];
    const float* Z_raw   = (const float*)d_in[3];
    float* out = (float*)d_out;
    int Bq = in_sizes[0] / 5;

    char* ws = (char*)d_ws;
    double* Kd   = (double*)(ws + OFF_K);
    double* Wd   = (double*)(ws + OFF_W);
    double* pd   = (double*)(ws + OFF_PD);
    float*  pf   = (float*)(ws + OFF_PF);
    double* Zsd  = (double*)(ws + OFF_ZD);
    float*  Zst  = (float*)(ws + OFF_ZT);
    short*  Wph  = (short*)(ws + OFF_WPH);
    short*  Wpl  = (short*)(ws + OFF_WPL);
    float*  redp = (float*)(ws + OFF_RED);

    k_prep<<<1, 64, 0, stream>>>(log_ls, log_var, pd, pf);
    k_prep_z<<<M_N / 256, 256, 0, stream>>>(Z_raw, pd, Zsd, Zst);
    k_build_K<<<dim3(M_N / 16, M_N / 16), dim3(16, 16), 0, stream>>>(Zsd, pd, Kd);

    for (int kb = 0; kb < NBK; ++kb) {
        k_chol_diag<<<1, 1024, 0, stream>>>(Kd, Wd, kb);
        int R = M_N - (kb + 1) * BS;
        if (R > 0) {
            k_chol_panel<<<R / 64, 256, 0, stream>>>(Kd, Wd, kb);
            k_chol_update<<<dim3(R / 64, R / 64), 256, 0, stream>>>(Kd, kb);
        }
    }
    for (int dd = 1; dd < NBK; ++dd)
        k_trtri<<<dim3(2, NBK - dd), 256, 0, stream>>>(Kd, Wd, dd);

    k_pack<<<(M_N * M_N / 8) / 256, 256, 0, stream>>>(Wd, Wph, Wpl);

    int slabs = (Bq + 63) / 64;
    k_mm<<<dim3(slabs, 2), 256, 0, stream>>>(x_star, pf, Zst, Wph, Wpl, redp, Bq);
    k_fin<<<(Bq + 255) / 256, 256, 0, stream>>>(redp, pf, out, Bq);
}

// Round 3
// 5392.624 us; speedup vs baseline: 1.6686x; 1.0955x over previous
//
#include <hip/hip_runtime.h>
#include <math.h>

// Sizes fixed by the problem.
#define B_TOT 131072
#define M_N   1024
#define BS    128      // Cholesky block size
#define NBK   8        // M_N / BS

typedef float  f32x4  __attribute__((ext_vector_type(4)));
typedef short  bf16x8 __attribute__((ext_vector_type(8)));

// Workspace layout (bytes). Total ~21.2 MB.
enum : size_t {
    OFF_K  = 0,                          // fp64 K / L           8 MB
    OFF_W  = (size_t)8 << 20,            // fp64 W = L^-1        8 MB
    OFF_PD = (size_t)16 << 20,           // fp64 params (6)
    OFF_PF = ((size_t)16 << 20) + 256,   // fp32 params (6)
    OFF_ZD = ((size_t)16 << 20) + 512,   // fp64 Zs [1024][5]    40960
    OFF_ZT = OFF_ZD + (size_t)M_N * 5 * 8,   // fp32 Zs_t [5][1024]  20480
    OFF_WPH = OFF_ZT + (size_t)M_N * 5 * 4,  // bf16 W packed hi     2 MB
    OFF_WPL = OFF_WPH + (size_t)M_N * M_N * 2,  // bf16 W packed lo  2 MB
};

__device__ __constant__ double c_zscale[5] = {0.15, 0.1, 0.05, 800.0, 20.0};
__device__ __constant__ double c_zshift[5] = {0.0, 0.0, 0.0, 600.0, 5.0};

static __device__ __forceinline__ unsigned short f2bf(float f) {
    unsigned u = __float_as_uint(f);
    unsigned r = (u + 0x7fff + ((u >> 16) & 1)) >> 16;   // RNE
    return (unsigned short)r;
}
static __device__ __forceinline__ float bf2f(unsigned short s) {
    return __uint_as_float(((unsigned)s) << 16);
}

// ---------------- params: inv_ls, prior_var (fp64 + fp32) ----------------
__global__ void k_prep(const float* __restrict__ log_ls, const float* __restrict__ log_var,
                       double* __restrict__ pd, float* __restrict__ pf) {
    int t = threadIdx.x;
    if (t < 5) {
        double ls  = exp((double)log_ls[t]);
        double inv = 1.0 / (ls + 1e-8);
        pd[t] = inv; pf[t] = (float)inv;
    }
    if (t == 5) {
        double pv = exp((double)log_var[0]);
        pd[5] = pv; pf[5] = (float)pv;
    }
}

// ---------------- scaled inducing points ----------------
__global__ void k_prep_z(const float* __restrict__ Zraw, const double* __restrict__ pd,
                         double* __restrict__ Zs_d, float* __restrict__ Zs_t) {
    int m = blockIdx.x * 256 + threadIdx.x;
    if (m >= M_N) return;
#pragma unroll
    for (int d = 0; d < 5; ++d) {
        double z  = (double)Zraw[m * 5 + d] * c_zscale[d] + c_zshift[d];
        double zs = z * pd[d];
        Zs_d[m * 5 + d]  = zs;
        Zs_t[d * M_N + m] = (float)zs;
    }
}

// ---------------- K = matern52 + jitter (fp64) ----------------
__global__ void k_build_K(const double* __restrict__ Zs_d, const double* __restrict__ pd,
                          double* __restrict__ Kd) {
    int i = blockIdx.y * 16 + threadIdx.y;
    int j = blockIdx.x * 16 + threadIdx.x;
    double d2 = 0.0;
#pragma unroll
    for (int d = 0; d < 5; ++d) {
        double df = Zs_d[i * 5 + d] - Zs_d[j * 5 + d];
        d2 += df * df;
    }
    double dd = d2 + 1e-8;
    double dist = sqrt(dd);
    double s = 2.2360679774997896 * dist;
    double v = pd[5] * (1.0 + s + (5.0 / 3.0) * dd) * exp(-s);
    if (i == j) v += 1e-4;
    Kd[(size_t)i * M_N + j] = v;
}

// ---------------- Cholesky diag block (128 thr, thread-per-row, 8-col panels)
//                  + barrier-free W11 = inv(L11) (column-owned, X in upper tri) ---------
__global__ __launch_bounds__(128) void k_chol_diag(double* __restrict__ Kd,
                                                   double* __restrict__ Wd, int kb) {
    __shared__ double As[128][129];   // lower: A/L ; upper [c][r] (r>c): X = inv(L)
    __shared__ double sinv[128];      // 1/L[j][j]
    int tid = threadIdx.x;
    int r0 = kb * BS;
    for (int idx = tid; idx < 128 * 128; idx += 128) {
        int rr = idx >> 7, cc = idx & 127;
        As[rr][cc] = Kd[(size_t)(r0 + rr) * M_N + r0 + cc];
    }
    __syncthreads();

    int r = tid;
    // ---- right-looking panel Cholesky ----
    for (int p = 0; p < 16; ++p) {
        int j0 = p * 8;
        for (int j = j0; j < j0 + 8; ++j) {
            if (r == j) {
                double d = sqrt(As[j][j]);
                As[j][j] = d;
                sinv[j] = 1.0 / d;
            }
            __syncthreads();
            double arj = 0.0;
            if (r > j) {
                arj = As[r][j] * sinv[j];
                As[r][j] = arj;
            }
            __syncthreads();
            if (r > j) {
                for (int c = j + 1; c < j0 + 8; ++c)   // in-panel rank-1
                    As[r][c] -= arj * As[c][j];        // As[c][j]: broadcast
            }
        }
        __syncthreads();
        // rank-8 trailing update of columns right of the panel
        if (r >= j0 + 8) {
            double a[8];
#pragma unroll
            for (int t = 0; t < 8; ++t) a[t] = As[r][j0 + t];
            for (int c = j0 + 8; c <= r; ++c) {
                double s = As[r][c];
#pragma unroll
                for (int t = 0; t < 8; ++t) s -= a[t] * As[c][j0 + t];   // broadcast
                As[r][c] = s;
            }
        }
        __syncthreads();
    }

    // ---- W11 = inv(L11): thread c owns column c; X[t][c] -> As[c][t] (t>c) ----
    int c = tid;
    for (int rb = 0; rb < 16; ++rb) {
        int r0b = rb * 8;
        if (c >= r0b + 8) continue;    // this row block is entirely above column c
        double s[8];
#pragma unroll
        for (int i = 0; i < 8; ++i) s[i] = 0.0;
        for (int t = 0; t < r0b; ++t) {
            if (t >= c) {
                double xt = (t == c) ? sinv[c] : As[c][t];   // X[t][c] (own writes)
#pragma unroll
                for (int i = 0; i < 8; ++i) s[i] += As[r0b + i][t] * xt;  // L: broadcast
            }
        }
        double xloc[8];
#pragma unroll
        for (int i = 0; i < 8; ++i) {
            int rr = r0b + i;
            double v = 0.0;
            if (rr >= c) {
                v = ((rr == c) ? 1.0 : 0.0) - s[i];
#pragma unroll
                for (int t2 = 0; t2 < i; ++t2) {
                    int tt = r0b + t2;
                    if (tt >= c) v -= As[rr][tt] * xloc[t2];
                }
                v *= sinv[rr];
                if (rr > c) As[c][rr] = v;
            }
            xloc[i] = v;
        }
    }
    __syncthreads();
    // write out W11 (lower incl. diag)
    for (int idx = tid; idx < 128 * 128; idx += 128) {
        int rr = idx >> 7, cc = idx & 127;
        if (rr >= cc)
            Wd[(size_t)(r0 + rr) * M_N + r0 + cc] = (rr == cc) ? sinv[rr] : As[cc][rr];
    }
}

// ---------------- panel: L21 = A21 * W11^T ----------------
__global__ __launch_bounds__(256) void k_chol_panel(double* __restrict__ Kd,
                                                    const double* __restrict__ Wd, int kb) {
    __shared__ double As[64][16];
    __shared__ double Ws[16][128];
    int tid = threadIdx.x;
    int row0 = (kb + 1) * BS + blockIdx.x * 64;
    int cb = kb * BS;
    int c = tid & 127, q = tid >> 7;
    double acc[32];
#pragma unroll
    for (int i = 0; i < 32; ++i) acc[i] = 0.0;
    for (int tc = 0; tc < 8; ++tc) {
        int tb = tc * 16;
        for (int idx = tid; idx < 64 * 16; idx += 256) {
            int rr = idx >> 4, tt = idx & 15;
            As[rr][tt] = Kd[(size_t)(row0 + rr) * M_N + cb + tb + tt];
        }
        for (int idx = tid; idx < 128 * 16; idx += 256) {
            int cc = idx >> 4, tt = idx & 15;
            Ws[tt][cc] = (tb + tt <= cc) ? Wd[(size_t)(cb + cc) * M_N + cb + tb + tt] : 0.0;
        }
        __syncthreads();
#pragma unroll
        for (int t = 0; t < 16; ++t) {
            double w = Ws[t][c];
#pragma unroll
            for (int i = 0; i < 32; ++i) acc[i] += As[q * 32 + i][t] * w;
        }
        __syncthreads();
    }
#pragma unroll
    for (int i = 0; i < 32; ++i)
        Kd[(size_t)(row0 + q * 32 + i) * M_N + cb + c] = acc[i];
}

// ---------------- trailing update: A22 -= L21 * L21^T ----------------
__global__ __launch_bounds__(256) void k_chol_update(double* __restrict__ Kd, int kb) {
    if (blockIdx.x > blockIdx.y) return;
    __shared__ double As2[64][17];
    __shared__ double Bs2[64][17];
    int tid = threadIdx.x;
    int base = (kb + 1) * BS;
    int gr0 = base + blockIdx.y * 64;
    int gc0 = base + blockIdx.x * 64;
    int cb = kb * BS;
    int tx = tid & 15, ty = tid >> 4;
    double acc[4][4];
#pragma unroll
    for (int i = 0; i < 4; ++i)
#pragma unroll
        for (int j = 0; j < 4; ++j) acc[i][j] = 0.0;
    for (int tc = 0; tc < 8; ++tc) {
        int tb = tc * 16;
        for (int idx = tid; idx < 1024; idx += 256) {
            int rr = idx >> 4, tt = idx & 15;
            As2[rr][tt] = Kd[(size_t)(gr0 + rr) * M_N + cb + tb + tt];
            Bs2[rr][tt] = Kd[(size_t)(gc0 + rr) * M_N + cb + tb + tt];
        }
        __syncthreads();
#pragma unroll
        for (int t = 0; t < 16; ++t) {
            double a[4], b[4];
#pragma unroll
            for (int i = 0; i < 4; ++i) a[i] = As2[ty * 4 + i][t];
#pragma unroll
            for (int j = 0; j < 4; ++j) b[j] = Bs2[tx * 4 + j][t];
#pragma unroll
            for (int i = 0; i < 4; ++i)
#pragma unroll
                for (int j = 0; j < 4; ++j) acc[i][j] += a[i] * b[j];
        }
        __syncthreads();
    }
#pragma unroll
    for (int i = 0; i < 4; ++i)
#pragma unroll
        for (int j = 0; j < 4; ++j)
            Kd[(size_t)(gr0 + ty * 4 + i) * M_N + gc0 + tx * 4 + j] -= acc[i][j];
}

// ---------------- trtri off-diag blocks ----------------
__global__ __launch_bounds__(256) void k_trtri(const double* __restrict__ Kd,
                                               double* __restrict__ Wd, int dd) {
    __shared__ double Ls[128][33];
    __shared__ double Ws2[32][65];
    __shared__ double Ps[128][65];
    int j = blockIdx.y;
    int i = j + dd;
    int ct = blockIdx.x;
    int i0 = i * BS, j0 = j * BS, c0 = j0 + ct * 64;
    int tid = threadIdx.x;
    int rq = tid >> 3, cq = tid & 7;
    double acc[4][8];
#pragma unroll
    for (int k = 0; k < 4; ++k)
#pragma unroll
        for (int c = 0; c < 8; ++c) acc[k][c] = 0.0;

    for (int tb = j; tb < i; ++tb) {
        for (int ch = 0; ch < 4; ++ch) {
            int tbase = tb * BS + ch * 32;
            for (int idx = tid; idx < 128 * 32; idx += 256) {
                int rr = idx >> 5, tt = idx & 31;
                Ls[rr][tt] = Kd[(size_t)(i0 + rr) * M_N + tbase + tt];
            }
            for (int idx = tid; idx < 32 * 64; idx += 256) {
                int tt = idx >> 6, cc = idx & 63;
                int gr = tbase + tt, gc = c0 + cc;
                Ws2[tt][cc] = (tb == j && gr < gc) ? 0.0 : Wd[(size_t)gr * M_N + gc];
            }
            __syncthreads();
#pragma unroll
            for (int tt = 0; tt < 32; ++tt) {
                double l_[4];
#pragma unroll
                for (int k = 0; k < 4; ++k) l_[k] = Ls[rq + 32 * k][tt];
#pragma unroll
                for (int k = 0; k < 4; ++k)
#pragma unroll
                    for (int c = 0; c < 8; ++c)
                        acc[k][c] += l_[k] * Ws2[tt][cq * 8 + c];
            }
            __syncthreads();
        }
    }
#pragma unroll
    for (int k = 0; k < 4; ++k)
#pragma unroll
        for (int c = 0; c < 8; ++c) Ps[rq + 32 * k][cq * 8 + c] = acc[k][c];
    __syncthreads();

    double a2[4][8];
#pragma unroll
    for (int k = 0; k < 4; ++k)
#pragma unroll
        for (int c = 0; c < 8; ++c) a2[k][c] = 0.0;
    for (int ch = 0; ch < 4; ++ch) {
        for (int idx = tid; idx < 128 * 32; idx += 256) {
            int rr = idx >> 5, tt = idx & 31;
            int col = ch * 32 + tt;
            Ls[rr][tt] = (col <= rr) ? Wd[(size_t)(i0 + rr) * M_N + i0 + col] : 0.0;
        }
        __syncthreads();
#pragma unroll
        for (int tt = 0; tt < 32; ++tt) {
            double l_[4];
#pragma unroll
            for (int k = 0; k < 4; ++k) l_[k] = Ls[rq + 32 * k][tt];
#pragma unroll
            for (int k = 0; k < 4; ++k)
#pragma unroll
                for (int c = 0; c < 8; ++c)
                    a2[k][c] += l_[k] * Ps[ch * 32 + tt][cq * 8 + c];
        }
        __syncthreads();
    }
#pragma unroll
    for (int k = 0; k < 4; ++k)
#pragma unroll
        for (int c = 0; c < 8; ++c)
            Wd[(size_t)(i0 + rq + 32 * k) * M_N + c0 + cq * 8 + c] = -a2[k][c];
}

// ---------------- pack W into MFMA B-fragment order, bf16 hi/lo ----------------
// fid = ((kc*4 + ki)*64 + jn); lane l elem e:
//   B[k = kc*128 + ki*32 + (l>>4)*8 + e][j = jn*16 + (l&15)] = W[j][k] (0 if k > j)
__global__ void k_pack(const double* __restrict__ Wd, short* __restrict__ Wph,
                       short* __restrict__ Wpl) {
    int T = blockIdx.x * 256 + threadIdx.x;
    int lane = T & 63, fid = T >> 6;
    int jn = fid & 63, kik = fid >> 6;
    int ki = kik & 3, kc = kik >> 2;
    int j  = jn * 16 + (lane & 15);
    int kb = kc * 128 + ki * 32 + (lane >> 4) * 8;
    bf16x8 h, lo;
#pragma unroll
    for (int e = 0; e < 8; ++e) {
        int k = kb + e;
        float v = (k <= j) ? (float)Wd[(size_t)j * M_N + k] : 0.0f;
        unsigned short hb = f2bf(v);
        h[e]  = (short)hb;
        lo[e] = (short)f2bf(v - bf2f(hb));
    }
    size_t off = (size_t)fid * 512 + lane * 8;
    *(bf16x8*)(Wph + off) = h;
    *(bf16x8*)(Wpl + off) = lo;
}

// ---------------- main MFMA kernel: 64 rows x 1024 cols per block, dbuf LDS ----------------
__global__ __launch_bounds__(512) void k_mm(const float* __restrict__ x_star,
                                            const float* __restrict__ pf,
                                            const float* __restrict__ Zs_t,
                                            const short* __restrict__ Wph,
                                            const short* __restrict__ Wpl,
                                            float* __restrict__ out, int Bq) {
    __shared__ char kls[2][2][64 * 256];   // [dbuf][hi/lo][row][256B], byte ^= (row&15)<<4
    __shared__ float xs[64][5];
    __shared__ float red_l[64];
    int tid  = threadIdx.x;
    int slab = blockIdx.x;
    int w = tid >> 6, lane = tid & 63;
    int lrow = lane & 15, kgrp = lane >> 4;

    if (tid < 64) {
        int qrow = slab * 64 + tid;
        int qc = (qrow < Bq) ? qrow : (Bq - 1);
#pragma unroll
        for (int d = 0; d < 5; ++d) xs[tid][d] = x_star[(size_t)qc * 5 + d] * pf[d];
        red_l[tid] = 0.0f;
    }
    float pv = pf[5];
    __syncthreads();

    auto stage = [&](int kc, char (*buf)[64 * 256]) {
#pragma unroll
        for (int p = 0; p < 2; ++p) {
            int idx = p * 512 + tid;
            int row = idx >> 4, cc = idx & 15;
            float x0 = xs[row][0], x1 = xs[row][1], x2 = xs[row][2],
                  x3 = xs[row][3], x4 = xs[row][4];
            int lb = kc * 128 + cc * 8;
            float z0[8], z1[8], z2[8], z3[8], z4[8];
            *(float4*)&z0[0] = *(const float4*)&Zs_t[lb];
            *(float4*)&z0[4] = *(const float4*)&Zs_t[lb + 4];
            *(float4*)&z1[0] = *(const float4*)&Zs_t[M_N + lb];
            *(float4*)&z1[4] = *(const float4*)&Zs_t[M_N + lb + 4];
            *(float4*)&z2[0] = *(const float4*)&Zs_t[2 * M_N + lb];
            *(float4*)&z2[4] = *(const float4*)&Zs_t[2 * M_N + lb + 4];
            *(float4*)&z3[0] = *(const float4*)&Zs_t[3 * M_N + lb];
            *(float4*)&z3[4] = *(const float4*)&Zs_t[3 * M_N + lb + 4];
            *(float4*)&z4[0] = *(const float4*)&Zs_t[4 * M_N + lb];
            *(float4*)&z4[4] = *(const float4*)&Zs_t[4 * M_N + lb + 4];
            bf16x8 hv, lv;
#pragma unroll
            for (int e = 0; e < 8; ++e) {
                float dx0 = x0 - z0[e], dx1 = x1 - z1[e], dx2 = x2 - z2[e],
                      dx3 = x3 - z3[e], dx4 = x4 - z4[e];
                float d2 = dx0 * dx0 + dx1 * dx1 + dx2 * dx2 + dx3 * dx3 + dx4 * dx4;
                float ddv = d2 + 1e-8f;
                float dist = sqrtf(ddv);
                float sv = 2.23606798f * dist;
                float kvf = pv * (1.0f + sv + 1.66666667f * ddv) * __expf(-sv);
                unsigned short hb = f2bf(kvf);
                hv[e] = (short)hb;
                lv[e] = (short)f2bf(kvf - bf2f(hb));
            }
            int off = row * 256 + ((cc * 16) ^ ((row & 15) << 4));
            *(bf16x8*)(&buf[0][off]) = hv;
            *(bf16x8*)(&buf[1][off]) = lv;
        }
    };

    f32x4 acc[4][8];
#pragma unroll
    for (int mi = 0; mi < 4; ++mi)
#pragma unroll
        for (int nj = 0; nj < 8; ++nj) acc[mi][nj] = (f32x4)(0.0f);

    int jng_max = 56 + ((w + 7) & 7);
    int jmax_w  = jng_max * 16 + 15;

    stage(0, kls[0]);
    __syncthreads();

    for (int kc = 0; kc < 8; ++kc) {
        if (kc < 7) stage(kc + 1, kls[(kc + 1) & 1]);
        char (*cur)[64 * 256] = kls[kc & 1];
        for (int ki = 0; ki < 4; ++ki) {
            int kmin = kc * 128 + ki * 32;
            if (kmin > jmax_w) break;            // wave-uniform
            bf16x8 Ah[4], Al[4];
#pragma unroll
            for (int mi = 0; mi < 4; ++mi) {
                int row = mi * 16 + lrow;
                int cb  = ki * 64 + kgrp * 16;
                int off = row * 256 + (cb ^ ((row & 15) << 4));
                Ah[mi] = *(const bf16x8*)(&cur[0][off]);
                Al[mi] = *(const bf16x8*)(&cur[1][off]);
            }
#pragma unroll
            for (int nj = 0; nj < 8; ++nj) {
                int jng = nj * 8 + ((w + nj) & 7);    // balanced col interleave
                if (kmin > jng * 16 + 15) continue;   // all-zero W fragment
                size_t fo = ((size_t)((kc * 4 + ki) * 64 + jng)) * 512 + lane * 8;
                bf16x8 Bh = *(const bf16x8*)(Wph + fo);
                bf16x8 Bl = *(const bf16x8*)(Wpl + fo);
#pragma unroll
                for (int mi = 0; mi < 4; ++mi) {
                    acc[mi][nj] = __builtin_amdgcn_mfma_f32_16x16x32_bf16(Ah[mi], Bh, acc[mi][nj], 0, 0, 0);
                    acc[mi][nj] = __builtin_amdgcn_mfma_f32_16x16x32_bf16(Ah[mi], Bl, acc[mi][nj], 0, 0, 0);
                    acc[mi][nj] = __builtin_amdgcn_mfma_f32_16x16x32_bf16(Al[mi], Bh, acc[mi][nj], 0, 0, 0);
                }
            }
        }
        __syncthreads();
    }

    // epilogue: red[row] += y^2 ; C layout: row = mi*16 + kgrp*4 + q, col = jng*16 + lrow
#pragma unroll
    for (int mi = 0; mi < 4; ++mi) {
#pragma unroll
        for (int q = 0; q < 4; ++q) {
            float s = 0.0f;
#pragma unroll
            for (int nj = 0; nj < 8; ++nj) s = fmaf(acc[mi][nj][q], acc[mi][nj][q], s);
            s += __shfl_xor(s, 1);
            s += __shfl_xor(s, 2);
            s += __shfl_xor(s, 4);
            s += __shfl_xor(s, 8);
            if (lrow == 0) atomicAdd(&red_l[mi * 16 + kgrp * 4 + q], s);
        }
    }
    __syncthreads();
    if (tid < 64) {
        int b = slab * 64 + tid;
        if (b < Bq) out[b] = sqrtf(fmaxf(pv - red_l[tid], 1e-6f));
    }
}

extern "C" void kernel_launch(void* const* d_in, const int* in_sizes, int n_in,
                              void* d_out, int out_size, void* d_ws, size_t ws_size,
                              hipStream_t stream) {
    const float* x_star  = (const float*)d_in[0];
    const float* log_ls  = (const float*)d_in[1];
    const float* log_var = (const float*)d_in[2];
    const float* Z_raw   = (const float*)d_in[3];
    float* out = (float*)d_out;
    int Bq = in_sizes[0] / 5;

    char* ws = (char*)d_ws;
    double* Kd   = (double*)(ws + OFF_K);
    double* Wd   = (double*)(ws + OFF_W);
    double* pd   = (double*)(ws + OFF_PD);
    float*  pf   = (float*)(ws + OFF_PF);
    double* Zsd  = (double*)(ws + OFF_ZD);
    float*  Zst  = (float*)(ws + OFF_ZT);
    short*  Wph  = (short*)(ws + OFF_WPH);
    short*  Wpl  = (short*)(ws + OFF_WPL);

    k_prep<<<1, 64, 0, stream>>>(log_ls, log_var, pd, pf);
    k_prep_z<<<M_N / 256, 256, 0, stream>>>(Z_raw, pd, Zsd, Zst);
    k_build_K<<<dim3(M_N / 16, M_N / 16), dim3(16, 16), 0, stream>>>(Zsd, pd, Kd);

    for (int kb = 0; kb < NBK; ++kb) {
        k_chol_diag<<<1, 128, 0, stream>>>(Kd, Wd, kb);
        int R = M_N - (kb + 1) * BS;
        if (R > 0) {
            k_chol_panel<<<R / 64, 256, 0, stream>>>(Kd, Wd, kb);
            k_chol_update<<<dim3(R / 64, R / 64), 256, 0, stream>>>(Kd, kb);
        }
    }
    for (int dd = 1; dd < NBK; ++dd)
        k_trtri<<<dim3(2, NBK - dd), 256, 0, stream>>>(Kd, Wd, dd);

    k_pack<<<(M_N * M_N / 8) / 256, 256, 0, stream>>>(Wd, Wph, Wpl);

    int slabs = (Bq + 63) / 64;
    k_mm<<<slabs, 512, 0, stream>>>(x_star, pf, Zst, Wph, Wpl, out, Bq);
}